// Round 10
// baseline (548.449 us; speedup 1.0000x reference)
//
#include <hip/hip_runtime.h>

#define NUM_GRAPHS 1024
#define BIN_BITS 10
#define BIN_SIZE (1 << BIN_BITS)      // 1024 nodes per bin
#define EB 8192                       // edges per binning block
#define STH 512                       // scatter threads (8 waves)
#define EPT 16                        // edges per thread in scatter (EB/STH)
#define ATH 1024                      // accum threads (= nodes per bin)
#define ACH 8192                      // accum chunk edges
#define IPT 8                         // items per thread in radix (ACH/ATH)

typedef int v4i __attribute__((ext_vector_type(4)));  // native vec for nt-load

// ---------------------------------------------------------------------------
// Prep: cursors to bin bases, zero pool accumulators, x -> packed bf16x4
// (8 B/node, 3.8 MB: fits every XCD L2 -> accum gather is cache-resident).
// ---------------------------------------------------------------------------
__device__ inline unsigned bf16_rn(float f) {
    unsigned u = __float_as_uint(f);
    return (u + 0x7FFFu + ((u >> 16) & 1u)) >> 16;
}
__global__ void prep_kernel(const float4* __restrict__ x, uint2* __restrict__ x16,
                            int N, int* __restrict__ cursor,
                            float* __restrict__ gsum, float* __restrict__ gcnt,
                            int cap) {
    int i = blockIdx.x * blockDim.x + threadIdx.x;
    if (i < 512) cursor[i] = i * cap;
    if (i < NUM_GRAPHS * 4) gsum[i] = 0.0f;
    if (i < NUM_GRAPHS) gcnt[i] = 0.0f;
    if (i < N) {
        float4 v = x[i];
        uint2 r;
        r.x = bf16_rn(v.x) | (bf16_rn(v.y) << 16);
        r.y = bf16_rn(v.z) | (bf16_rn(v.w) << 16);
        x16[i] = r;
    }
}

// ---------------------------------------------------------------------------
// bin_scatter v5 (unchanged from r9): rtn-atomic histogram pass, placement by
// plain LDS writes, sbin table flush. packed = (dst_local << 19) | src.
// ---------------------------------------------------------------------------
__global__ void __launch_bounds__(STH) bin_scatter(const int* __restrict__ src,
                                                   const int* __restrict__ dst,
                                                   int* __restrict__ packed,
                                                   int* __restrict__ cursor,
                                                   int E, int cap, int nb) {
    __shared__ int shist[512];
    __shared__ int sprefix[513];
    __shared__ int sgbase[512];
    __shared__ int spacked[EB];
    __shared__ unsigned short sbin[EB];
    __shared__ int wsum[8];

    const int t = threadIdx.x;
    const int lane = t & 63;
    const int wave = t >> 6;
    const int b0 = blockIdx.x * EB;
    const int myBase = b0 + t * EPT;

    for (int j = t; j < 512; j += STH) shist[j] = 0;
    __syncthreads();

    int pv[EPT];
    int bl[EPT];
    const bool full = (myBase + EPT <= E);
    if (full) {
#pragma unroll
        for (int v = 0; v < EPT / 4; ++v) {
            int4 d = *(const int4*)(dst + myBase + v * 4);
            int4 s = *(const int4*)(src + myBase + v * 4);
            int bn, lp;
            bn = ((unsigned)d.x) >> BIN_BITS; lp = atomicAdd(&shist[bn], 1);
            pv[v * 4 + 0] = ((d.x & (BIN_SIZE - 1)) << 19) | s.x;
            bl[v * 4 + 0] = (bn << 13) | lp;
            bn = ((unsigned)d.y) >> BIN_BITS; lp = atomicAdd(&shist[bn], 1);
            pv[v * 4 + 1] = ((d.y & (BIN_SIZE - 1)) << 19) | s.y;
            bl[v * 4 + 1] = (bn << 13) | lp;
            bn = ((unsigned)d.z) >> BIN_BITS; lp = atomicAdd(&shist[bn], 1);
            pv[v * 4 + 2] = ((d.z & (BIN_SIZE - 1)) << 19) | s.z;
            bl[v * 4 + 2] = (bn << 13) | lp;
            bn = ((unsigned)d.w) >> BIN_BITS; lp = atomicAdd(&shist[bn], 1);
            pv[v * 4 + 3] = ((d.w & (BIN_SIZE - 1)) << 19) | s.w;
            bl[v * 4 + 3] = (bn << 13) | lp;
        }
    } else {
#pragma unroll
        for (int i = 0; i < EPT; ++i) {
            int e = myBase + i;
            bool ok = e < E;
            int d = ok ? dst[e] : 0;
            int s = ok ? src[e] : 0;
            int bn = ((unsigned)d) >> BIN_BITS;
            int lp = 0;
            if (ok) lp = atomicAdd(&shist[bn], 1);
            pv[i] = ((d & (BIN_SIZE - 1)) << 19) | s;
            bl[i] = ok ? ((bn << 13) | lp) : -1;
        }
    }
    __syncthreads();

    {
        int v = shist[t];
        int inc = v;
#pragma unroll
        for (int off = 1; off < 64; off <<= 1) {
            int u = __shfl_up(inc, off);
            if (lane >= off) inc += u;
        }
        if (lane == 63) wsum[wave] = inc;
        __syncthreads();
        if (t == 0) {
            int acc = 0;
#pragma unroll
            for (int w = 0; w < 8; ++w) { int c = wsum[w]; wsum[w] = acc; acc += c; }
        }
        __syncthreads();
        sprefix[t + 1] = inc + wsum[wave];
        if (t == 0) sprefix[0] = 0;
        if (t < nb && v > 0) sgbase[t] = atomicAdd(&cursor[t], v);
    }
    __syncthreads();

    if (full) {
#pragma unroll
        for (int i = 0; i < EPT; ++i) {
            int bn = ((unsigned)bl[i]) >> 13;
            int lp = bl[i] & 0x1FFF;
            int idx = sprefix[bn] + lp;
            spacked[idx] = pv[i];
            sbin[idx] = (unsigned short)bn;
        }
    } else {
#pragma unroll
        for (int i = 0; i < EPT; ++i) {
            if (bl[i] >= 0) {
                int bn = ((unsigned)bl[i]) >> 13;
                int lp = bl[i] & 0x1FFF;
                int idx = sprefix[bn] + lp;
                spacked[idx] = pv[i];
                sbin[idx] = (unsigned short)bn;
            }
        }
    }
    __syncthreads();

    int cnt = sprefix[nb < 512 ? nb : 512];
    int totE = E - b0; if (totE < 0) totE = 0;
    if (cnt > totE) cnt = totE;
    for (int j = t; j < cnt; j += STH) {
        int bn = sbin[j];
        int pos = sgbase[bn] + (j - sprefix[bn]);
        if (pos < (bn + 1) * cap)
            __builtin_nontemporal_store(spacked[j], &packed[pos]);
    }
}

// ---------------------------------------------------------------------------
// Accum v6 + MLP + pool: ATOMIC-FREE. Per 8192-edge chunk: load into bufA,
// 5-pass radix-4 LSD sort on dl bits 19..28 (per-thread reg histograms,
// shfl scans, plain LDS scatter — no DS atomics, which cost ~4 cyc/lane),
// binary-search segment bounds, consume own node's segment gathering
// L2-resident bf16x4 x16[src]. Padding = 0xFFFFFFFF (dl=1023, stable after
// real edges; je clamped to cnt).
// ---------------------------------------------------------------------------
__global__ void __launch_bounds__(ATH) bin_accum_mlp_pool(
        const float4* __restrict__ x,
        const uint2* __restrict__ x16,
        const int* __restrict__ packed,
        const int* __restrict__ cursor,
        const int* __restrict__ batch,
        const float* __restrict__ eps_p,
        const float* __restrict__ W1, const float* __restrict__ b1,
        const float* __restrict__ W2, const float* __restrict__ b2,
        float* __restrict__ gsum, float* __restrict__ gcnt,
        int N, int cap) {
    __shared__ int bufA[ACH];           // 32 KB ping
    __shared__ int bufB[ACH];           // 32 KB pong
    __shared__ int pfx[BIN_SIZE + 1];   // 4 KB segment bounds
    __shared__ int warr[32];            // packed wave totals (16 waves x 2)
    __shared__ int wpre[32];            // exclusive wave prefixes
    __shared__ int gtot[2];             // grand totals (packed)

    const int bin = blockIdx.x;
    const int t = threadIdx.x;
    const int lane = t & 63;
    const int wave = t >> 6;

    const int start = bin * cap;
    int end = cursor[bin];
    if (end > start + cap) end = start + cap;

    float a0 = 0.f, a1 = 0.f, a2 = 0.f, a3 = 0.f;

#pragma unroll 1
    for (int cs = start; cs < end; cs += ACH) {
        int ce = cs + ACH; if (ce > end) ce = end;
        const int cnt = ce - cs;

        // ---- load chunk into bufA (coalesced 16B), pad with 0xFFFFFFFF ----
#pragma unroll
        for (int i = 0; i < IPT / 4; ++i) {
            int ebase = cs + (i * ATH + t) * 4;
            v4i p4;
            if (ebase + 3 < ce) {
                p4 = __builtin_nontemporal_load((const v4i*)(packed + ebase));
            } else {
                p4.x = (ebase + 0 < ce) ? packed[ebase + 0] : -1;
                p4.y = (ebase + 1 < ce) ? packed[ebase + 1] : -1;
                p4.z = (ebase + 2 < ce) ? packed[ebase + 2] : -1;
                p4.w = (ebase + 3 < ce) ? packed[ebase + 3] : -1;
            }
            *(v4i*)&bufA[ebase - cs] = p4;
        }
        __syncthreads();

        // ---- 5-pass radix-4 stable LSD sort on bits 19..28 ----
#pragma unroll
        for (int pass = 0; pass < 5; ++pass) {
            const int shift = 19 + 2 * pass;
            int* rb = (pass & 1) ? bufB : bufA;   // const-folded after unroll
            int* wb = (pass & 1) ? bufA : bufB;

            v4i k0 = *(const v4i*)&rb[t * IPT];
            v4i k1 = *(const v4i*)&rb[t * IPT + 4];
            int k[IPT] = {k0.x, k0.y, k0.z, k0.w, k1.x, k1.y, k1.z, k1.w};

            int c0 = 0, c1 = 0, c2 = 0, c3 = 0;
            int r[IPT];
#pragma unroll
            for (int i = 0; i < IPT; ++i) {
                int d = (((unsigned)k[i]) >> shift) & 3;
                int rr;
                if (d == 0)      { rr = c0; c0++; }
                else if (d == 1) { rr = c1; c1++; }
                else if (d == 2) { rr = c2; c2++; }
                else             { rr = c3; c3++; }
                r[i] = rr;
            }
            int P0 = c0 | (c1 << 16), P1 = c2 | (c3 << 16);
            int s0 = P0, s1 = P1;
#pragma unroll
            for (int off = 1; off < 64; off <<= 1) {
                int u0 = __shfl_up(s0, off);
                int u1 = __shfl_up(s1, off);
                if (lane >= off) { s0 += u0; s1 += u1; }
            }
            if (lane == 63) { warr[wave * 2] = s0; warr[wave * 2 + 1] = s1; }
            int e0 = s0 - P0, e1 = s1 - P1;     // intra-wave exclusive (packed)
            __syncthreads();

            if (wave == 0 && lane < 16) {
                int v0 = warr[lane * 2], v1 = warr[lane * 2 + 1];
                int t0 = v0, t1 = v1;
#pragma unroll
                for (int off = 1; off < 16; off <<= 1) {
                    int u0 = __shfl_up(t0, off);
                    int u1 = __shfl_up(t1, off);
                    if (lane >= off) { t0 += u0; t1 += u1; }
                }
                wpre[lane * 2] = t0 - v0;
                wpre[lane * 2 + 1] = t1 - v1;
                if (lane == 15) { gtot[0] = t0; gtot[1] = t1; }
            }
            __syncthreads();

            int w0 = wpre[wave * 2], w1 = wpre[wave * 2 + 1];
            int T0 = gtot[0], T1 = gtot[1];
            int tot0 = T0 & 0xFFFF, tot1 = (T0 >> 16) & 0xFFFF, tot2 = T1 & 0xFFFF;
            int g0 = 0                   + (w0 & 0xFFFF)         + (e0 & 0xFFFF);
            int g1 = tot0                + ((w0 >> 16) & 0xFFFF) + ((e0 >> 16) & 0xFFFF);
            int g2 = tot0 + tot1         + (w1 & 0xFFFF)         + (e1 & 0xFFFF);
            int g3 = tot0 + tot1 + tot2  + ((w1 >> 16) & 0xFFFF) + ((e1 >> 16) & 0xFFFF);
#pragma unroll
            for (int i = 0; i < IPT; ++i) {
                int d = (((unsigned)k[i]) >> shift) & 3;
                int base = (d == 0) ? g0 : (d == 1) ? g1 : (d == 2) ? g2 : g3;
                wb[base + r[i]] = k[i];
            }
            __syncthreads();
        }
        // after 5 passes sorted data lives in bufB

        // ---- segment bounds: lower_bound of dl == t ----
        {
            int lo = 0, hi = ACH;
            while (lo < hi) {
                int mid = (lo + hi) >> 1;
                int dl = (((unsigned)bufB[mid]) >> 19) & 0x3FF;
                if (dl < t) lo = mid + 1; else hi = mid;
            }
            pfx[t] = lo;
            if (t == 0) pfx[BIN_SIZE] = ACH;
        }
        __syncthreads();

        // ---- consume own segment: bf16x4 gather (L2-resident) ----
        int jb = pfx[t];
        int je = pfx[t + 1];
        if (je > cnt) je = cnt;   // only trims node 1023's padding tail
        for (int j = jb; j < je; ++j) {
            int s = bufB[j] & 0x7FFFF;
            uint2 v = x16[s];
            a0 += __uint_as_float(v.x << 16);
            a1 += __uint_as_float(v.x & 0xFFFF0000u);
            a2 += __uint_as_float(v.y << 16);
            a3 += __uint_as_float(v.y & 0xFFFF0000u);
        }
        __syncthreads();   // protect buffers before next chunk
    }

    // ---- MLP + pool from register accumulator (self term in f32) ----
    int n = bin * BIN_SIZE + t;
    bool valid = n < N;
    float o0 = 0.f, o1 = 0.f, o2 = 0.f, o3 = 0.f;
    int g = -1;
    if (valid) {
        float eps = eps_p[0];
        float4 xv = x[n];
        float h0 = (1.0f + eps) * xv.x + a0;
        float h1 = (1.0f + eps) * xv.y + a1;
        float h2 = (1.0f + eps) * xv.z + a2;
        float h3 = (1.0f + eps) * xv.w + a3;

        float tmp[16];
#pragma unroll
        for (int j = 0; j < 16; ++j) {
            float v = b1[j] + h0 * W1[j] + h1 * W1[16 + j] + h2 * W1[32 + j] + h3 * W1[48 + j];
            tmp[j] = v > 0.0f ? v : 0.0f;
        }
        float o[4];
#pragma unroll
        for (int j = 0; j < 4; ++j) {
            float v = b2[j];
#pragma unroll
            for (int k = 0; k < 16; ++k) v += tmp[k] * W2[k * 4 + j];
            o[j] = v > 0.0f ? v : 0.0f;
        }
        o0 = o[0]; o1 = o[1]; o2 = o[2]; o3 = o[3];
        g = batch[n];
    }

    int g0 = __shfl(g, 0);
    bool uni = __all(g == g0);
    if (uni && g0 >= 0) {
#pragma unroll
        for (int off = 32; off > 0; off >>= 1) {
            o0 += __shfl_down(o0, off);
            o1 += __shfl_down(o1, off);
            o2 += __shfl_down(o2, off);
            o3 += __shfl_down(o3, off);
        }
        if ((t & 63) == 0) {
            unsafeAtomicAdd(&gsum[(size_t)g0 * 4 + 0], o0);
            unsafeAtomicAdd(&gsum[(size_t)g0 * 4 + 1], o1);
            unsafeAtomicAdd(&gsum[(size_t)g0 * 4 + 2], o2);
            unsafeAtomicAdd(&gsum[(size_t)g0 * 4 + 3], o3);
            unsafeAtomicAdd(&gcnt[g0], 64.0f);
        }
    } else if (valid) {
        unsafeAtomicAdd(&gsum[(size_t)g * 4 + 0], o0);
        unsafeAtomicAdd(&gsum[(size_t)g * 4 + 1], o1);
        unsafeAtomicAdd(&gsum[(size_t)g * 4 + 2], o2);
        unsafeAtomicAdd(&gsum[(size_t)g * 4 + 3], o3);
        unsafeAtomicAdd(&gcnt[g], 1.0f);
    }
}

// ---------------------------------------------------------------------------
// pooled = sums / max(cnt,1); out = log_softmax per graph.
// ---------------------------------------------------------------------------
__global__ void pool_softmax_kernel(const float* __restrict__ gsum,
                                    const float* __restrict__ gcnt,
                                    float* __restrict__ out) {
    int g = blockIdx.x * blockDim.x + threadIdx.x;
    if (g >= NUM_GRAPHS) return;
    float c = fmaxf(gcnt[g], 1.0f);
    float p0 = gsum[g * 4 + 0] / c;
    float p1 = gsum[g * 4 + 1] / c;
    float p2 = gsum[g * 4 + 2] / c;
    float p3 = gsum[g * 4 + 3] / c;
    float m = fmaxf(fmaxf(p0, p1), fmaxf(p2, p3));
    float s = expf(p0 - m) + expf(p1 - m) + expf(p2 - m) + expf(p3 - m);
    float lse = m + logf(s);
    out[g * 4 + 0] = p0 - lse;
    out[g * 4 + 1] = p1 - lse;
    out[g * 4 + 2] = p2 - lse;
    out[g * 4 + 3] = p3 - lse;
}

// ---------------------------------------------------------------------------
// Fallback kernels (ws too small): direct atomic scatter + separate MLP/pool.
// ---------------------------------------------------------------------------
__global__ void edge_scatter_kernel(const float4* __restrict__ x,
                                    const int* __restrict__ src,
                                    const int* __restrict__ dst,
                                    float* __restrict__ agg,
                                    int E) {
    int t = blockIdx.x * blockDim.x + threadIdx.x;
    int e = t * 4;
    if (e + 3 < E) {
        int4 s = *(const int4*)(src + e);
        int4 d = *(const int4*)(dst + e);
        float4 xv;
        xv = x[s.x];
        unsafeAtomicAdd(&agg[(size_t)d.x * 4 + 0], xv.x);
        unsafeAtomicAdd(&agg[(size_t)d.x * 4 + 1], xv.y);
        unsafeAtomicAdd(&agg[(size_t)d.x * 4 + 2], xv.z);
        unsafeAtomicAdd(&agg[(size_t)d.x * 4 + 3], xv.w);
        xv = x[s.y];
        unsafeAtomicAdd(&agg[(size_t)d.y * 4 + 0], xv.x);
        unsafeAtomicAdd(&agg[(size_t)d.y * 4 + 1], xv.y);
        unsafeAtomicAdd(&agg[(size_t)d.y * 4 + 2], xv.z);
        unsafeAtomicAdd(&agg[(size_t)d.y * 4 + 3], xv.w);
        xv = x[s.z];
        unsafeAtomicAdd(&agg[(size_t)d.z * 4 + 0], xv.x);
        unsafeAtomicAdd(&agg[(size_t)d.z * 4 + 1], xv.y);
        unsafeAtomicAdd(&agg[(size_t)d.z * 4 + 2], xv.z);
        unsafeAtomicAdd(&agg[(size_t)d.z * 4 + 3], xv.w);
        xv = x[s.w];
        unsafeAtomicAdd(&agg[(size_t)d.w * 4 + 0], xv.x);
        unsafeAtomicAdd(&agg[(size_t)d.w * 4 + 1], xv.y);
        unsafeAtomicAdd(&agg[(size_t)d.w * 4 + 2], xv.z);
        unsafeAtomicAdd(&agg[(size_t)d.w * 4 + 3], xv.w);
    } else {
        for (int i = e; i < E; ++i) {
            int sv = src[i], dv = dst[i];
            float4 xv = x[sv];
            unsafeAtomicAdd(&agg[(size_t)dv * 4 + 0], xv.x);
            unsafeAtomicAdd(&agg[(size_t)dv * 4 + 1], xv.y);
            unsafeAtomicAdd(&agg[(size_t)dv * 4 + 2], xv.z);
            unsafeAtomicAdd(&agg[(size_t)dv * 4 + 3], xv.w);
        }
    }
}

__global__ void node_mlp_pool_kernel(const float4* __restrict__ x,
                                     const float4* __restrict__ agg,
                                     const int* __restrict__ batch,
                                     const float* __restrict__ eps_p,
                                     const float* __restrict__ W1,
                                     const float* __restrict__ b1,
                                     const float* __restrict__ W2,
                                     const float* __restrict__ b2,
                                     float* __restrict__ gsum,
                                     float* __restrict__ gcnt,
                                     int N) {
    int i = blockIdx.x * blockDim.x + threadIdx.x;
    bool valid = i < N;
    float o0 = 0.f, o1 = 0.f, o2 = 0.f, o3 = 0.f;
    int g = -1;
    if (valid) {
        float eps = eps_p[0];
        float4 xv = x[i];
        float4 av = agg[i];
        float h0 = (1.0f + eps) * xv.x + av.x;
        float h1 = (1.0f + eps) * xv.y + av.y;
        float h2 = (1.0f + eps) * xv.z + av.z;
        float h3 = (1.0f + eps) * xv.w + av.w;
        float tmp[16];
#pragma unroll
        for (int j = 0; j < 16; ++j) {
            float v = b1[j] + h0 * W1[j] + h1 * W1[16 + j] + h2 * W1[32 + j] + h3 * W1[48 + j];
            tmp[j] = v > 0.0f ? v : 0.0f;
        }
        float o[4];
#pragma unroll
        for (int j = 0; j < 4; ++j) {
            float v = b2[j];
#pragma unroll
            for (int k = 0; k < 16; ++k) v += tmp[k] * W2[k * 4 + j];
            o[j] = v > 0.0f ? v : 0.0f;
        }
        o0 = o[0]; o1 = o[1]; o2 = o[2]; o3 = o[3];
        g = batch[i];
    }
    int g0 = __shfl(g, 0);
    bool uni = __all(g == g0);
    if (uni && g0 >= 0) {
#pragma unroll
        for (int off = 32; off > 0; off >>= 1) {
            o0 += __shfl_down(o0, off);
            o1 += __shfl_down(o1, off);
            o2 += __shfl_down(o2, off);
            o3 += __shfl_down(o3, off);
        }
        if ((threadIdx.x & 63) == 0) {
            unsafeAtomicAdd(&gsum[(size_t)g0 * 4 + 0], o0);
            unsafeAtomicAdd(&gsum[(size_t)g0 * 4 + 1], o1);
            unsafeAtomicAdd(&gsum[(size_t)g0 * 4 + 2], o2);
            unsafeAtomicAdd(&gsum[(size_t)g0 * 4 + 3], o3);
            unsafeAtomicAdd(&gcnt[g0], 64.0f);
        }
    } else if (valid) {
        unsafeAtomicAdd(&gsum[(size_t)g * 4 + 0], o0);
        unsafeAtomicAdd(&gsum[(size_t)g * 4 + 1], o1);
        unsafeAtomicAdd(&gsum[(size_t)g * 4 + 2], o2);
        unsafeAtomicAdd(&gsum[(size_t)g * 4 + 3], o3);
        unsafeAtomicAdd(&gcnt[g], 1.0f);
    }
}

extern "C" void kernel_launch(void* const* d_in, const int* in_sizes, int n_in,
                              void* d_out, int out_size, void* d_ws, size_t ws_size,
                              hipStream_t stream) {
    const float* x     = (const float*)d_in[0];
    const int*   ei    = (const int*)d_in[1];
    const int*   batch = (const int*)d_in[2];
    const float* eps   = (const float*)d_in[3];
    const float* W1    = (const float*)d_in[4];
    const float* b1    = (const float*)d_in[5];
    const float* W2    = (const float*)d_in[6];
    const float* b2    = (const float*)d_in[7];

    const int N = in_sizes[0] / 4;
    const int E = in_sizes[1] / 2;
    const int* src = ei;
    const int* dst = ei + (size_t)E;

    const int nb = (N + BIN_SIZE - 1) >> BIN_BITS;   // 489 for N=500K
    const int epb = (E + nb - 1) / nb;
    int cap = epb + epb / 8 + 1024;                  // ~28 sigma headroom
    cap = (cap + 3) & ~3;                            // 16B-align chunk bases

    size_t x16_elems = ((size_t)2 * N + 3) & ~(size_t)3;
    size_t packed_elems = ((size_t)nb * cap + 3) & ~(size_t)3;
    size_t need = (x16_elems + packed_elems + 512 + NUM_GRAPHS * 5) * sizeof(float);

    if (nb <= 512 && N < (1 << 19) && need <= ws_size) {
        uint2* x16    = (uint2*)d_ws;
        int*   packed = (int*)d_ws + x16_elems;
        int*   cursor = packed + packed_elems;
        float* gsum   = (float*)(cursor + 512);
        float* gcnt   = gsum + (size_t)NUM_GRAPHS * 4;

        prep_kernel<<<(N + 511) / 512, 512, 0, stream>>>(
            (const float4*)x, x16, N, cursor, gsum, gcnt, cap);

        int nblocks_e = (E + EB - 1) / EB;
        bin_scatter<<<nblocks_e, STH, 0, stream>>>(src, dst, packed, cursor, E, cap, nb);

        bin_accum_mlp_pool<<<nb, ATH, 0, stream>>>(
            (const float4*)x, (const uint2*)x16, packed, cursor, batch, eps,
            W1, b1, W2, b2, gsum, gcnt, N, cap);

        pool_softmax_kernel<<<(NUM_GRAPHS + 255) / 256, 256, 0, stream>>>(
            gsum, gcnt, (float*)d_out);
    } else {
        float* agg  = (float*)d_ws;
        float* gsum = agg + (size_t)N * 4;
        float* gcnt = gsum + (size_t)NUM_GRAPHS * 4;
        size_t zero_bytes = ((size_t)N * 4 + NUM_GRAPHS * 5) * sizeof(float);
        (void)hipMemsetAsync(d_ws, 0, zero_bytes, stream);

        int e4 = (E + 3) / 4;
        edge_scatter_kernel<<<(e4 + 255) / 256, 256, 0, stream>>>(
            (const float4*)x, src, dst, agg, E);

        node_mlp_pool_kernel<<<(N + 255) / 256, 256, 0, stream>>>(
            (const float4*)x, (const float4*)agg, batch, eps, W1, b1, W2, b2,
            gsum, gcnt, N);

        pool_softmax_kernel<<<(NUM_GRAPHS + 255) / 256, 256, 0, stream>>>(
            gsum, gcnt, (float*)d_out);
    }
}